// Round 1
// baseline (316.121 us; speedup 1.0000x reference)
//
#include <hip/hip_runtime.h>

typedef __bf16 bf16_t;
typedef __bf16 bf16x8 __attribute__((ext_vector_type(8)));
typedef __bf16 bf16x4 __attribute__((ext_vector_type(4)));
typedef float  floatx4 __attribute__((ext_vector_type(4)));

#define BM 128
#define BN 128
#define BK 32

__device__ __forceinline__ void gload_lds16(const bf16_t* g, bf16_t* l) {
    __builtin_amdgcn_global_load_lds(
        (const __attribute__((address_space(1))) void*)g,
        (__attribute__((address_space(3))) void*)l,
        16, 0, 0);
}

// C[m][n] = scale * sum_k A[m][k] * B[n][k]   (NT GEMM, all row-major, K-inner)
// Dims must be multiples of 128 (true for all uses here). batch via blockIdx.z.
template <typename OutT>
__global__ __launch_bounds__(256) void gemm_nt(
    const bf16_t* __restrict__ A, int lda, size_t batchA,
    const bf16_t* __restrict__ B, int ldb, size_t batchB,
    OutT* __restrict__ C, int ldc, size_t batchC,
    int K, float scale)
{
    __shared__ bf16_t sA[BM * BK];
    __shared__ bf16_t sB[BN * BK];

    A += (size_t)blockIdx.z * batchA;
    B += (size_t)blockIdx.z * batchB;
    C += (size_t)blockIdx.z * batchC;

    const int tid  = threadIdx.x;
    const int wid  = tid >> 6;       // wave 0..3
    const int lane = tid & 63;

    const int bm = blockIdx.x * BM;
    const int bn = blockIdx.y * BN;

    // staging: thread t loads 8 bf16 (16B); covers row t/4, k-offset (t%4)*8
    // within a 64-row chunk; 2 chunks per 128-row tile.
    const int sr = tid >> 2;
    const int sk = (tid & 3) * 8;

    // wave quadrant: 2x2 waves, each computes 64x64 via 4x4 MFMA 16x16 tiles
    const int wy = (wid >> 1) * 64;
    const int wx = (wid & 1) * 64;
    const int lr = lane & 15;        // m (or n) within 16
    const int lk = (lane >> 4) * 8;  // k fragment offset

    floatx4 acc[4][4] = {};

    const bf16_t* pa = A + (size_t)(bm + sr) * lda + sk;
    const bf16_t* pb = B + (size_t)(bn + sr) * ldb + sk;

    for (int k0 = 0; k0 < K; k0 += BK) {
        // global -> LDS: wave-uniform base + lane*16, row-major [128][32]
        #pragma unroll
        for (int c = 0; c < 2; ++c) {
            gload_lds16(pa + (size_t)(c * 64) * lda + k0, &sA[(c * 64 + wid * 16) * BK]);
            gload_lds16(pb + (size_t)(c * 64) * ldb + k0, &sB[(c * 64 + wid * 16) * BK]);
        }
        __syncthreads();

        bf16x8 af[4], bfr[4];
        #pragma unroll
        for (int i = 0; i < 4; ++i)
            af[i] = *(const bf16x8*)&sA[(wy + i * 16 + lr) * BK + lk];
        #pragma unroll
        for (int j = 0; j < 4; ++j)
            bfr[j] = *(const bf16x8*)&sB[(wx + j * 16 + lr) * BK + lk];

        #pragma unroll
        for (int i = 0; i < 4; ++i)
            #pragma unroll
            for (int j = 0; j < 4; ++j)
                acc[i][j] = __builtin_amdgcn_mfma_f32_16x16x32_bf16(
                    af[i], bfr[j], acc[i][j], 0, 0, 0);

        __syncthreads();
    }

    // C/D layout (m89-verified): col = lane&15, row = (lane>>4)*4 + reg
    const int cr = (lane >> 4) * 4;
    const int cc = lane & 15;
    #pragma unroll
    for (int i = 0; i < 4; ++i)
        #pragma unroll
        for (int j = 0; j < 4; ++j)
            #pragma unroll
            for (int r = 0; r < 4; ++r) {
                size_t row = (size_t)(bm + wy + i * 16 + cr + r);
                size_t col = (size_t)(bn + wx + j * 16 + cc);
                C[row * (size_t)ldc + col] = (OutT)(acc[i][j][r] * scale);
            }
}

__global__ __launch_bounds__(256) void cvt_f32_bf16(
    const float* __restrict__ in, bf16_t* __restrict__ out, int n4)
{
    int i = blockIdx.x * blockDim.x + threadIdx.x;
    if (i >= n4) return;
    float4 v = ((const float4*)in)[i];
    bf16x4 o;
    o[0] = (bf16_t)v.x; o[1] = (bf16_t)v.y; o[2] = (bf16_t)v.z; o[3] = (bf16_t)v.w;
    *(bf16x4*)(out + (size_t)i * 4) = o;
}

// one block per row of 2048 bf16 scores; in-place softmax
__global__ __launch_bounds__(256) void softmax_inplace(bf16_t* __restrict__ S, int ncols)
{
    __shared__ float red[4];
    bf16_t* p = S + (size_t)blockIdx.x * ncols;
    const int t = threadIdx.x;

    bf16x8 raw = *(const bf16x8*)&p[t * 8];
    float v[8];
    #pragma unroll
    for (int r = 0; r < 8; ++r) v[r] = (float)raw[r];

    float m = v[0];
    #pragma unroll
    for (int r = 1; r < 8; ++r) m = fmaxf(m, v[r]);
    #pragma unroll
    for (int off = 32; off >= 1; off >>= 1) m = fmaxf(m, __shfl_xor(m, off));
    if ((t & 63) == 0) red[t >> 6] = m;
    __syncthreads();
    m = fmaxf(fmaxf(red[0], red[1]), fmaxf(red[2], red[3]));
    __syncthreads();

    float e[8], s = 0.f;
    #pragma unroll
    for (int r = 0; r < 8; ++r) { e[r] = __expf(v[r] - m); s += e[r]; }
    #pragma unroll
    for (int off = 32; off >= 1; off >>= 1) s += __shfl_xor(s, off);
    if ((t & 63) == 0) red[t >> 6] = s;
    __syncthreads();
    s = red[0] + red[1] + red[2] + red[3];

    float inv = 1.0f / s;
    bf16x8 o;
    #pragma unroll
    for (int r = 0; r < 8; ++r) o[r] = (bf16_t)(e[r] * inv);
    *(bf16x8*)&p[t * 8] = o;
}

extern "C" void kernel_launch(void* const* d_in, const int* in_sizes, int n_in,
                              void* d_out, int out_size, void* d_ws, size_t ws_size,
                              hipStream_t stream)
{
    (void)in_sizes; (void)n_in; (void)out_size; (void)ws_size;
    const float* X  = (const float*)d_in[0];
    const float* Wq = (const float*)d_in[1];
    const float* Wk = (const float*)d_in[2];
    const float* Wv = (const float*)d_in[3];
    float* out = (float*)d_out;

    const int Bb = 4, S = 2048, D = 1024;
    const int M = Bb * S;  // 8192

    char* ws = (char*)d_ws;
    size_t off = 0;
    auto carve = [&](size_t bytes) -> char* {
        char* p = ws + off;
        off += (bytes + 255) & ~(size_t)255;
        return p;
    };
    bf16_t* Xb  = (bf16_t*)carve((size_t)M * D * 2);       // 16 MB
    bf16_t* Wqb = (bf16_t*)carve((size_t)D * D * 2);       // 2 MB
    bf16_t* Wkb = (bf16_t*)carve((size_t)D * D * 2);
    bf16_t* Wvb = (bf16_t*)carve((size_t)D * D * 2);
    bf16_t* Qb  = (bf16_t*)carve((size_t)M * D * 2);       // 16 MB
    bf16_t* Kb  = (bf16_t*)carve((size_t)M * D * 2);       // 16 MB
    bf16_t* Vt  = (bf16_t*)carve((size_t)D * M * 2);       // 16 MB (V^T: D x M)
    bf16_t* Sc  = (bf16_t*)carve((size_t)Bb * S * S * 2);  // 33.5 MB

    // fp32 -> bf16 conversions
    cvt_f32_bf16<<<(M * D / 4) / 256, 256, 0, stream>>>(X, Xb, M * D / 4);
    cvt_f32_bf16<<<(D * D / 4) / 256, 256, 0, stream>>>(Wq, Wqb, D * D / 4);
    cvt_f32_bf16<<<(D * D / 4) / 256, 256, 0, stream>>>(Wk, Wkb, D * D / 4);
    cvt_f32_bf16<<<(D * D / 4) / 256, 256, 0, stream>>>(Wv, Wvb, D * D / 4);

    // Q = X Wq^T, K = X Wk^T   (M x D)
    gemm_nt<bf16_t><<<dim3(M / BM, D / BN, 1), 256, 0, stream>>>(
        Xb, D, 0, Wqb, D, 0, Qb, D, 0, D, 1.0f);
    gemm_nt<bf16_t><<<dim3(M / BM, D / BN, 1), 256, 0, stream>>>(
        Xb, D, 0, Wkb, D, 0, Kb, D, 0, D, 1.0f);
    // V^T = Wv X^T   (D x M) — V stored transposed so PV GEMM is NT too
    gemm_nt<bf16_t><<<dim3(D / BM, M / BN, 1), 256, 0, stream>>>(
        Wvb, D, 0, Xb, D, 0, Vt, M, 0, D, 1.0f);

    // scores_b = (Q_b K_b^T) / 32   (B x S x S), bf16
    gemm_nt<bf16_t><<<dim3(S / BM, S / BN, Bb), 256, 0, stream>>>(
        Qb, D, (size_t)S * D, Kb, D, (size_t)S * D, Sc, S, (size_t)S * S,
        D, 0.03125f);

    // P = softmax(scores) in place
    softmax_inplace<<<Bb * S, 256, 0, stream>>>(Sc, S);

    // out_b = P_b V_b : A = P_b (S x S), B = V^T with column offset b*S (ldb = M)
    gemm_nt<float><<<dim3(S / BM, D / BN, Bb), 256, 0, stream>>>(
        Sc, S, (size_t)S * S, Vt, M, (size_t)S, out, D, (size_t)S * D,
        S, 1.0f);
}

// Round 2
// 277.857 us; speedup vs baseline: 1.1377x; 1.1377x over previous
//
#include <hip/hip_runtime.h>

typedef __bf16 bf16_t;
typedef __bf16 bf16x8 __attribute__((ext_vector_type(8)));
typedef __bf16 bf16x4 __attribute__((ext_vector_type(4)));
typedef float  floatx4 __attribute__((ext_vector_type(4)));

#define BM 128
#define BN 128
#define BK 64

__device__ __forceinline__ void gload_lds16(const bf16_t* g, bf16_t* l) {
    __builtin_amdgcn_global_load_lds(
        (const __attribute__((address_space(1))) void*)g,
        (__attribute__((address_space(3))) void*)l,
        16, 0, 0);
}

// C = scale * A * B^T (NT, row-major, K-contiguous operands).
// TRANSC=false: C[m][n] (ldc over n). TRANSC=true: C[n][m] (ldc over m).
// LDS tiles are [128][64] bf16 with XOR chunk swizzle: LDS slot (r, s)
// holds global 16B-chunk (r, s ^ (r&7)) so ds_read_b128 of 16 rows at a
// fixed k-chunk spreads over all 32 banks (max 2-way aliasing = free).
template <typename OutT, bool TRANSC>
__global__ __launch_bounds__(256) void gemm_nt(
    const bf16_t* __restrict__ A, int lda, size_t batchA,
    const bf16_t* __restrict__ B, int ldb, size_t batchB,
    OutT* __restrict__ C, int ldc, size_t batchC,
    int K, float scale)
{
    __shared__ bf16_t sA[BM * BK];
    __shared__ bf16_t sB[BN * BK];

    A += (size_t)blockIdx.z * batchA;
    B += (size_t)blockIdx.z * batchB;
    C += (size_t)blockIdx.z * batchC;

    const int tid  = threadIdx.x;
    const int wid  = tid >> 6;
    const int lane = tid & 63;

    const int bm = blockIdx.x * BM;
    const int bn = blockIdx.y * BN;

    // staging: thread t -> row (t>>3) within each 32-row chunk,
    // source k-chunk xor-swizzled by row
    const int rr  = tid >> 3;                       // 0..31
    const int kc8 = (((tid & 7) ^ (rr & 7)) << 3);  // element offset of 16B chunk

    const int wy = (wid >> 1) * 64;
    const int wx = (wid & 1) * 64;
    const int lr = lane & 15;

    floatx4 acc[4][4] = {};

    const bf16_t* pa = A + (size_t)(bm + rr) * lda + kc8;
    const bf16_t* pb = B + (size_t)(bn + rr) * ldb + kc8;
    bf16_t* la = &sA[wid * 512];   // wave covers 1 KiB (8 rows) per chunk
    bf16_t* lb = &sB[wid * 512];

    for (int k0 = 0; k0 < K; k0 += BK) {
        #pragma unroll
        for (int c = 0; c < 4; ++c) {
            gload_lds16(pa + (size_t)(c * 32) * lda + k0, la + c * 2048);
            gload_lds16(pb + (size_t)(c * 32) * ldb + k0, lb + c * 2048);
        }
        __syncthreads();

        #pragma unroll
        for (int kk = 0; kk < 2; ++kk) {
            const int cch = (kk << 2) + (lane >> 4);  // k-chunk index 0..7
            bf16x8 af[4], bq[4];
            #pragma unroll
            for (int i = 0; i < 4; ++i) {
                int r = wy + i * 16 + lr;
                af[i] = *(const bf16x8*)&sA[(r << 6) + ((cch ^ (r & 7)) << 3)];
            }
            #pragma unroll
            for (int j = 0; j < 4; ++j) {
                int r = wx + j * 16 + lr;
                bq[j] = *(const bf16x8*)&sB[(r << 6) + ((cch ^ (r & 7)) << 3)];
            }
            #pragma unroll
            for (int i = 0; i < 4; ++i)
                #pragma unroll
                for (int j = 0; j < 4; ++j) {
                    if constexpr (!TRANSC)
                        // D "row" dim (reg) = arg1 = B/n -> 4 consecutive cols
                        acc[i][j] = __builtin_amdgcn_mfma_f32_16x16x32_bf16(
                            bq[j], af[i], acc[i][j], 0, 0, 0);
                    else
                        // reg dim = A/m -> 4 consecutive cols of C^T
                        acc[i][j] = __builtin_amdgcn_mfma_f32_16x16x32_bf16(
                            af[i], bq[j], acc[i][j], 0, 0, 0);
                }
        }
        __syncthreads();
    }

    // epilogue: each thread owns 4 consecutive elements along the fast dim
    const int cfix = lane & 15;          // fixed dim within 16
    const int creg = (lane >> 4) << 2;   // reg-run base within 16
    #pragma unroll
    for (int i = 0; i < 4; ++i)
        #pragma unroll
        for (int j = 0; j < 4; ++j) {
            size_t row; int col;
            if constexpr (!TRANSC) {
                row = (size_t)(bm + wy + i * 16 + cfix);
                col = bn + wx + j * 16 + creg;
            } else {
                row = (size_t)(bn + wx + j * 16 + cfix);
                col = bm + wy + i * 16 + creg;
            }
            if constexpr (sizeof(OutT) == 2) {
                bf16x4 v;
                #pragma unroll
                for (int r = 0; r < 4; ++r) v[r] = (bf16_t)(acc[i][j][r] * scale);
                *(bf16x4*)&C[row * (size_t)ldc + col] = v;
            } else {
                floatx4 v = acc[i][j] * scale;
                *(floatx4*)&C[row * (size_t)ldc + col] = v;
            }
        }
}

// one fused fp32->bf16 conversion over X, Wq, Wk, Wv
__global__ __launch_bounds__(256) void cvt_all(
    const float* __restrict__ X, const float* __restrict__ Wq,
    const float* __restrict__ Wk, const float* __restrict__ Wv,
    bf16_t* __restrict__ Xb, bf16_t* __restrict__ Wqb,
    bf16_t* __restrict__ Wkb, bf16_t* __restrict__ Wvb,
    int nX4, int nW4)
{
    int i = blockIdx.x * blockDim.x + threadIdx.x;
    const float* src; bf16_t* dst; int idx;
    if (i < nX4) { src = X; dst = Xb; idx = i; }
    else {
        int j = i - nX4;
        int w = j / nW4;          // nW4 is a power of two -> shift
        idx = j - w * nW4;
        if (i >= nX4 + 3 * nW4) return;
        src = (w == 0) ? Wq : (w == 1) ? Wk : Wv;
        dst = (w == 0) ? Wqb : (w == 1) ? Wkb : Wvb;
    }
    float4 v = ((const float4*)src)[idx];
    bf16x4 o;
    o[0] = (bf16_t)v.x; o[1] = (bf16_t)v.y; o[2] = (bf16_t)v.z; o[3] = (bf16_t)v.w;
    *(bf16x4*)(dst + (size_t)idx * 4) = o;
}

// one block per row of 2048 bf16 scores; in-place softmax
__global__ __launch_bounds__(256) void softmax_inplace(bf16_t* __restrict__ S, int ncols)
{
    __shared__ float red[4];
    bf16_t* p = S + (size_t)blockIdx.x * ncols;
    const int t = threadIdx.x;

    bf16x8 raw = *(const bf16x8*)&p[t * 8];
    float v[8];
    #pragma unroll
    for (int r = 0; r < 8; ++r) v[r] = (float)raw[r];

    float m = v[0];
    #pragma unroll
    for (int r = 1; r < 8; ++r) m = fmaxf(m, v[r]);
    #pragma unroll
    for (int off = 32; off >= 1; off >>= 1) m = fmaxf(m, __shfl_xor(m, off));
    if ((t & 63) == 0) red[t >> 6] = m;
    __syncthreads();
    m = fmaxf(fmaxf(red[0], red[1]), fmaxf(red[2], red[3]));
    __syncthreads();

    float e[8], s = 0.f;
    #pragma unroll
    for (int r = 0; r < 8; ++r) { e[r] = __expf(v[r] - m); s += e[r]; }
    #pragma unroll
    for (int off = 32; off >= 1; off >>= 1) s += __shfl_xor(s, off);
    if ((t & 63) == 0) red[t >> 6] = s;
    __syncthreads();
    s = red[0] + red[1] + red[2] + red[3];

    float inv = 1.0f / s;
    bf16x8 o;
    #pragma unroll
    for (int r = 0; r < 8; ++r) o[r] = (bf16_t)(e[r] * inv);
    *(bf16x8*)&p[t * 8] = o;
}

extern "C" void kernel_launch(void* const* d_in, const int* in_sizes, int n_in,
                              void* d_out, int out_size, void* d_ws, size_t ws_size,
                              hipStream_t stream)
{
    (void)in_sizes; (void)n_in; (void)out_size; (void)ws_size;
    const float* X  = (const float*)d_in[0];
    const float* Wq = (const float*)d_in[1];
    const float* Wk = (const float*)d_in[2];
    const float* Wv = (const float*)d_in[3];
    float* out = (float*)d_out;

    const int Bb = 4, S = 2048, D = 1024;
    const int M = Bb * S;  // 8192

    char* ws = (char*)d_ws;
    size_t off = 0;
    auto carve = [&](size_t bytes) -> char* {
        char* p = ws + off;
        off += (bytes + 255) & ~(size_t)255;
        return p;
    };
    // NOTE: Wq/Wk adjacency (stride D*D) and Q/K adjacency (stride M*D) are
    // relied upon by the fused z=2 projection launch; both byte sizes are
    // multiples of 256 so carve() keeps them contiguous.
    bf16_t* Xb  = (bf16_t*)carve((size_t)M * D * 2);       // 16 MB
    bf16_t* Wqb = (bf16_t*)carve((size_t)D * D * 2);       // 2 MB
    bf16_t* Wkb = (bf16_t*)carve((size_t)D * D * 2);
    bf16_t* Wvb = (bf16_t*)carve((size_t)D * D * 2);
    bf16_t* Qb  = (bf16_t*)carve((size_t)M * D * 2);       // 16 MB
    bf16_t* Kb  = (bf16_t*)carve((size_t)M * D * 2);       // 16 MB
    bf16_t* Vt  = (bf16_t*)carve((size_t)D * M * 2);       // 16 MB (V^T: D x M)
    bf16_t* Sc  = (bf16_t*)carve((size_t)Bb * S * S * 2);  // 33.5 MB

    // fp32 -> bf16, all four tensors in one launch
    const int nX4 = M * D / 4, nW4 = D * D / 4;
    const int tot4 = nX4 + 3 * nW4;
    cvt_all<<<(tot4 + 255) / 256, 256, 0, stream>>>(
        X, Wq, Wk, Wv, Xb, Wqb, Wkb, Wvb, nX4, nW4);

    // Q = X Wq^T and K = X Wk^T in one z=2 dispatch (B strides Wq->Wk, C strides Q->K)
    gemm_nt<bf16_t, false><<<dim3(M / BM, D / BN, 2), 256, 0, stream>>>(
        Xb, D, 0, Wqb, D, (size_t)D * D, Qb, D, (size_t)M * D, D, 1.0f);

    // V^T = (X Wv^T)^T  (D x M), written transposed so PV GEMM stays NT
    gemm_nt<bf16_t, true><<<dim3(M / BM, D / BN, 1), 256, 0, stream>>>(
        Xb, D, 0, Wvb, D, 0, Vt, M, 0, D, 1.0f);

    // scores_b = (Q_b K_b^T) / 32   (B x S x S), bf16
    gemm_nt<bf16_t, false><<<dim3(S / BM, S / BN, Bb), 256, 0, stream>>>(
        Qb, D, (size_t)S * D, Kb, D, (size_t)S * D, Sc, S, (size_t)S * S,
        D, 0.03125f);

    // P = softmax(scores) in place
    softmax_inplace<<<Bb * S, 256, 0, stream>>>(Sc, S);

    // out_b = P_b V_b : B = V^T with column offset b*S (ldb = M)
    gemm_nt<float, false><<<dim3(S / BM, D / BN, Bb), 256, 0, stream>>>(
        Sc, S, (size_t)S * S, Vt, M, (size_t)S, out, D, (size_t)S * D,
        S, 1.0f);
}